// Round 3
// baseline (1527.495 us; speedup 1.0000x reference)
//
#include <hip/hip_runtime.h>

#define BB 8
#define SS 2048
#define DDIM 128
#define TM 16              // q rows per block (4 per wave)
#define KT 64              // k-tile rows staged in LDS (32 KiB)
#define NT (SS / KT)       // 32 tiles
#define NPK (SS / 64)      // 32 scores per lane per row; tile t <-> p=t (KT=64)

// compile-time for: guarantees constant indices into sc[][] (pragma unroll was
// NOT honored on the tile loop in R1/R2 -> dynamic index -> array in scratch,
// proven by VGPR_Count=56 < 64 live floats and WRITE_SIZE ~541 MB of scratch).
template <int I> struct IC { static constexpr int value = I; };
template <int I, int N, typename F>
__device__ __forceinline__ void sfor(F&& f) {
  if constexpr (I < N) {
    f(IC<I>{});
    sfor<I + 1, N>((F&&)f);
  }
}

// ---------------- V transpose: V[b][k][d] -> Vt[b][d][k] ----------------
__global__ __launch_bounds__(256)
void vtranspose(const float* __restrict__ V, float* __restrict__ Vt) {
  __shared__ float t[32][33];
  const int b  = blockIdx.z;
  const int d0 = blockIdx.x * 32;
  const int k0 = blockIdx.y * 32;
  const float* Vb  = V  + (size_t)b * SS * DDIM;
  float*       Vtb = Vt + (size_t)b * DDIM * SS;
  const int lx = threadIdx.x & 31;
  const int ly = threadIdx.x >> 5;   // 0..7
#pragma unroll
  for (int i = 0; i < 32; i += 8)
    t[ly + i][lx] = Vb[(size_t)(k0 + ly + i) * DDIM + d0 + lx];
  __syncthreads();
#pragma unroll
  for (int i = 0; i < 32; i += 8)
    Vtb[(size_t)(d0 + ly + i) * SS + k0 + lx] = t[lx][ly + i];
}

// ---------------- fused entmax attention ----------------
// Wave owns 4 q-rows x all 2048 k. Lane holds k = 64*p + lane, p in [0,32).
__global__ __launch_bounds__(256, 2)
void attn_fused(const float* __restrict__ Q, const float* __restrict__ K,
                const float* __restrict__ Vt, float* __restrict__ Out) {
  __shared__ float lds[KT * DDIM];   // 32 KiB; reused as V slice in phase 4

  const int tid  = threadIdx.x;
  const int lane = tid & 63;
  const int wid  = __builtin_amdgcn_readfirstlane(tid >> 6);  // uniform wave id
  const int b    = blockIdx.x & 7;        // batch -> XCD pinning (round-robin)
  const int qt   = blockIdx.x >> 3;       // 0..127

  const float* Qw  = Q  + (size_t)(b * SS + qt * TM + wid * 4) * DDIM;  // uniform
  const float* Kb  = K  + (size_t)b * SS * DDIM;
  const float* Vtb = Vt + (size_t)b * DDIM * SS;
  float*       Ow  = Out + (size_t)(b * SS + qt * TM + wid * 4) * DDIM;

  float sc[4][NPK];   // 128 VGPRs -- every access below has a constexpr index

  const int swz = lane & 31;

  // ---------- phase 1: scores = Q K^T ----------
  sfor<0, NT>([&](auto tc) {
    constexpr int T = tc.value;
    __syncthreads();
    {
      const float4* src = (const float4*)(Kb + (size_t)T * KT * DDIM);
      const int c4   = tid & 31;
      const int row0 = tid >> 5;
#pragma unroll
      for (int i = 0; i < 8; ++i) {        // 64 rows x 128 d = 32 KiB
        const int row = row0 + i * 8;
        float4 v = src[row * 32 + c4];
        *(float4*)&lds[row * DDIM + ((c4 ^ (row & 31)) << 2)] = v;
      }
    }
    __syncthreads();
    float a0 = 0.f, a1 = 0.f, a2 = 0.f, a3 = 0.f;   // scalar accumulators
    for (int c = 0; c < 32; ++c) {   // rolled: d-chunk of 4
      const int sw = (c ^ swz) << 2;
      const float4 k0 = *(const float4*)&lds[lane * DDIM + sw];  // 0 conflicts (measured)
      const float4 q0 = *(const float4*)&Qw[0 * DDIM + c * 4];   // uniform -> s_load
      const float4 q1 = *(const float4*)&Qw[1 * DDIM + c * 4];
      const float4 q2 = *(const float4*)&Qw[2 * DDIM + c * 4];
      const float4 q3 = *(const float4*)&Qw[3 * DDIM + c * 4];
      a0 = fmaf(q0.x, k0.x, a0); a0 = fmaf(q0.y, k0.y, a0);
      a0 = fmaf(q0.z, k0.z, a0); a0 = fmaf(q0.w, k0.w, a0);
      a1 = fmaf(q1.x, k0.x, a1); a1 = fmaf(q1.y, k0.y, a1);
      a1 = fmaf(q1.z, k0.z, a1); a1 = fmaf(q1.w, k0.w, a1);
      a2 = fmaf(q2.x, k0.x, a2); a2 = fmaf(q2.y, k0.y, a2);
      a2 = fmaf(q2.z, k0.z, a2); a2 = fmaf(q2.w, k0.w, a2);
      a3 = fmaf(q3.x, k0.x, a3); a3 = fmaf(q3.y, k0.y, a3);
      a3 = fmaf(q3.z, k0.z, a3); a3 = fmaf(q3.w, k0.w, a3);
    }
    sc[0][T] = a0; sc[1][T] = a1; sc[2][T] = a2; sc[3][T] = a3;
  });

  // ---------- phase 2: z = 0.5*s, row max, bisection ----------
  float tmin[4], tmax[4], tau[4], Z[4];
  sfor<0, 4>([&](auto rc) {
    constexpr int r = rc.value;
    float m = -1e30f;
    sfor<0, NPK>([&](auto pc) {
      constexpr int p = pc.value;
      sc[r][p] *= 0.5f;                    // (alpha-1)*scores
      m = fmaxf(m, sc[r][p]);
    });
#pragma unroll
    for (int s = 1; s <= 32; s <<= 1) m = fmaxf(m, __shfl_xor(m, s));
    tmin[r] = m - 1.0f;
    tmax[r] = m - 0.022097086912079608f;   // S^(1-alpha) = 2048^-0.5
    tau[r]  = 0.5f * (tmin[r] + tmax[r]);
    Z[r]    = 0.f;
  });

  for (int it = 0; it < 100; ++it) {
    bool changed = false;
    sfor<0, 4>([&](auto rc) {
      constexpr int r = rc.value;
      const float tr = 0.5f * (tmin[r] + tmax[r]);
      tau[r] = tr;
      float zp = 0.f;
      sfor<0, NPK>([&](auto pc) {
        constexpr int p = pc.value;
        const float tt = fmaxf(sc[r][p] - tr, 0.f);
        zp = fmaf(tt, tt, zp);
      });
#pragma unroll
      for (int s = 1; s <= 32; s <<= 1) zp += __shfl_xor(zp, s);
      Z[r] = zp;
      const float nmin = (zp >= 1.f) ? tr : tmin[r];
      const float nmax = (zp >= 1.f) ? tmax[r] : tr;
      changed = changed || (nmin != tmin[r]) || (nmax != tmax[r]);
      tmin[r] = nmin;
      tmax[r] = nmax;
    });
    if (!changed) break;   // fixed point: bit-identical to running all 100 iters
  }

  // ---------- phase 3: weights = max(z-tau,0)^2 / Z ----------
  sfor<0, 4>([&](auto rc) {
    constexpr int r = rc.value;
    const float invZ = 1.0f / Z[r];
    sfor<0, NPK>([&](auto pc) {
      constexpr int p = pc.value;
      const float tt = fmaxf(sc[r][p] - tau[r], 0.f);
      sc[r][p] = tt * tt * invZ;
    });
  });

  // ---------- phase 4: out = weights @ V ----------
  for (int c = 0; c < 32; ++c) {       // d-chunk of 4
    __syncthreads();
#pragma unroll
    for (int s = 0; s < 8; ++s) {      // stage V slice [2048][4] = 32 KiB
      const int k = s * 256 + tid;
      float4 v;
      v.x = Vtb[(size_t)(c * 4 + 0) * SS + k];
      v.y = Vtb[(size_t)(c * 4 + 1) * SS + k];
      v.z = Vtb[(size_t)(c * 4 + 2) * SS + k];
      v.w = Vtb[(size_t)(c * 4 + 3) * SS + k];
      *(float4*)&lds[k * 4] = v;
    }
    __syncthreads();
    float acc[4][4];
    sfor<0, 4>([&](auto rc) {
      sfor<0, 4>([&](auto jc) { acc[rc.value][jc.value] = 0.f; });
    });
    sfor<0, NPK>([&](auto pc) {
      constexpr int p = pc.value;
      const float4 v = *(const float4*)&lds[(p * 64 + lane) * 4];
      sfor<0, 4>([&](auto rc) {
        constexpr int r = rc.value;
        acc[r][0] = fmaf(sc[r][p], v.x, acc[r][0]);
        acc[r][1] = fmaf(sc[r][p], v.y, acc[r][1]);
        acc[r][2] = fmaf(sc[r][p], v.z, acc[r][2]);
        acc[r][3] = fmaf(sc[r][p], v.w, acc[r][3]);
      });
    });
#pragma unroll
    for (int s = 1; s <= 32; s <<= 1)
      sfor<0, 4>([&](auto rc) {
        sfor<0, 4>([&](auto jc) {
          acc[rc.value][jc.value] += __shfl_xor(acc[rc.value][jc.value], s);
        });
      });
    if (lane < 16) {
      const int r = lane >> 2, j = lane & 3;
      float v = acc[0][0];
      sfor<0, 4>([&](auto rc) {
        sfor<0, 4>([&](auto jc) {
          if (r == rc.value && j == jc.value) v = acc[rc.value][jc.value];
        });
      });
      Ow[r * DDIM + c * 4 + j] = v;
    }
  }
}

extern "C" void kernel_launch(void* const* d_in, const int* in_sizes, int n_in,
                              void* d_out, int out_size, void* d_ws, size_t ws_size,
                              hipStream_t stream) {
  const float* Q = (const float*)d_in[0];
  const float* K = (const float*)d_in[1];
  const float* V = (const float*)d_in[2];
  float* out = (float*)d_out;
  float* Vt  = (float*)d_ws;   // 8 MiB: Vt[b][d][k]

  dim3 tg(DDIM / 32, SS / 32, BB);          // 4 x 64 x 8
  hipLaunchKernelGGL(vtranspose, tg, dim3(256), 0, stream, V, Vt);

  const int grid = BB * (SS / TM);          // 1024 blocks
  hipLaunchKernelGGL(attn_fused, dim3(grid), dim3(256), 0, stream, Q, K, Vt, out);
}

// Round 4
// 589.025 us; speedup vs baseline: 2.5933x; 2.5933x over previous
//
#include <hip/hip_runtime.h>

#define BB 8
#define SS 2048
#define DDIM 128
#define TM 8               // q rows per block
#define KRANGE 512         // k-range owned by each wave (4 waves x 512 = 2048)

// Fused entmax-1.5 attention. Scores live in LDS (64 KB), never in a big
// register array (R1-R3: the allocator refuses to promote a 128-elem array
// across the bisection loop -> 0.5-0.7 GB of scratch traffic; fix is
// structural: per-thread live set <= ~20 values).
__global__ __launch_bounds__(256, 2)
void attn_fused(const float* __restrict__ Q, const float* __restrict__ K,
                const float* __restrict__ V, float* __restrict__ Out) {
  __shared__ float zbuf[TM][SS];     // 64 KB: z = 0.5*scores, then weights
  __shared__ float tauZ[2][TM];      // tau, Z broadcast between waves

  const int tid  = threadIdx.x;
  const int lane = tid & 63;
  const int wid  = __builtin_amdgcn_readfirstlane(tid >> 6);  // 0..3, uniform
  const int b    = blockIdx.x & 7;        // batch -> XCD pinning
  const int qt   = blockIdx.x >> 3;       // 0..255

  const float* Qb = Q + (size_t)(b * SS + qt * TM) * DDIM;    // uniform
  const float* Kb = K + (size_t)b * SS * DDIM;
  const float* Vb = V + (size_t)b * SS * DDIM;
  float*       Ob = Out + (size_t)(b * SS + qt * TM) * DDIM;

  const int wb = wid * KRANGE;       // wave's k-range base

  // ---------- phase 1: z[r][k] = 0.5 * dot(Q[r], K[k]) for k in wave range ----
  // Lane owns k = wb + 64p + lane; K row streamed as float4 (L1-cached window);
  // 8-row reuse per K element. Q loads are wave-uniform -> scalar path.
  for (int p = 0; p < 8; ++p) {
    const int k = wb + p * 64 + lane;
    const float4* Krow = (const float4*)(Kb + (size_t)k * DDIM);
    float a[TM];
#pragma unroll
    for (int r = 0; r < TM; ++r) a[r] = 0.f;
#pragma unroll 8
    for (int c = 0; c < 32; ++c) {
      const float4 kv = Krow[c];
#pragma unroll
      for (int r = 0; r < TM; ++r) {
        const float4 qv = *(const float4*)&Qb[r * DDIM + c * 4];
        a[r] = fmaf(qv.x, kv.x, a[r]);
        a[r] = fmaf(qv.y, kv.y, a[r]);
        a[r] = fmaf(qv.z, kv.z, a[r]);
        a[r] = fmaf(qv.w, kv.w, a[r]);
      }
    }
#pragma unroll
    for (int r = 0; r < TM; ++r) zbuf[r][k] = a[r] * 0.5f;  // fold (alpha-1)
  }
  __syncthreads();

  // ---------- phase 2: bisection for rows {2w, 2w+1}, z re-read from LDS ----
  float tmin[2], tmax[2], tauv[2], Zv[2];
#pragma unroll
  for (int rr = 0; rr < 2; ++rr) {
    const int r = wid * 2 + rr;
    const float4* zr = (const float4*)zbuf[r];
    float m = -1e30f;
#pragma unroll
    for (int j = 0; j < 8; ++j) {
      const float4 z4 = zr[j * 64 + lane];
      m = fmaxf(m, fmaxf(fmaxf(z4.x, z4.y), fmaxf(z4.z, z4.w)));
    }
#pragma unroll
    for (int s = 1; s <= 32; s <<= 1) m = fmaxf(m, __shfl_xor(m, s));
    tmin[rr] = m - 1.0f;
    tmax[rr] = m - 0.022097086912079608f;   // S^(1-alpha) = 2048^-0.5
    tauv[rr] = 0.5f * (tmin[rr] + tmax[rr]);
    Zv[rr]   = 0.f;
  }

  for (int it = 0; it < 100; ++it) {
    bool changed = false;
#pragma unroll
    for (int rr = 0; rr < 2; ++rr) {
      const int r = wid * 2 + rr;
      const float4* zr = (const float4*)zbuf[r];
      const float tr = 0.5f * (tmin[rr] + tmax[rr]);
      tauv[rr] = tr;
      float zp = 0.f;
#pragma unroll
      for (int j = 0; j < 8; ++j) {
        const float4 z4 = zr[j * 64 + lane];
        float t0 = fmaxf(z4.x - tr, 0.f); zp = fmaf(t0, t0, zp);
        float t1 = fmaxf(z4.y - tr, 0.f); zp = fmaf(t1, t1, zp);
        float t2 = fmaxf(z4.z - tr, 0.f); zp = fmaf(t2, t2, zp);
        float t3 = fmaxf(z4.w - tr, 0.f); zp = fmaf(t3, t3, zp);
      }
#pragma unroll
      for (int s = 1; s <= 32; s <<= 1) zp += __shfl_xor(zp, s);
      Zv[rr] = zp;
      const float nmin = (zp >= 1.f) ? tr : tmin[rr];
      const float nmax = (zp >= 1.f) ? tmax[rr] : tr;
      changed = changed || (nmin != tmin[rr]) || (nmax != tmax[rr]);
      tmin[rr] = nmin;
      tmax[rr] = nmax;
    }
    if (!changed) break;   // fixed point: bit-identical to running all 100
  }
  if (lane == 0) {
#pragma unroll
    for (int rr = 0; rr < 2; ++rr) {
      tauZ[0][wid * 2 + rr] = tauv[rr];
      tauZ[1][wid * 2 + rr] = Zv[rr];
    }
  }
  __syncthreads();

  // ---------- phase 3: weights = max(z-tau,0)^2/Z on wave's own k-slab ------
#pragma unroll
  for (int r = 0; r < TM; ++r) {
    const float tr = tauZ[0][r];
    const float iz = 1.0f / tauZ[1][r];
    float4* zr = (float4*)zbuf[r];
#pragma unroll
    for (int j = 0; j < 2; ++j) {
      const int idx = wb / 4 + j * 64 + lane;
      float4 z4 = zr[idx];
      float t0 = fmaxf(z4.x - tr, 0.f); z4.x = t0 * t0 * iz;
      float t1 = fmaxf(z4.y - tr, 0.f); z4.y = t1 * t1 * iz;
      float t2 = fmaxf(z4.z - tr, 0.f); z4.z = t2 * t2 * iz;
      float t3 = fmaxf(z4.w - tr, 0.f); z4.w = t3 * t3 * iz;
      zr[idx] = z4;
    }
  }
  // no barrier needed: phase 4 reads only this wave's own slab

  // ---------- phase 4: partial O over wave's k-range, V rows coalesced ------
  float o[TM][2];
#pragma unroll
  for (int r = 0; r < TM; ++r) { o[r][0] = 0.f; o[r][1] = 0.f; }

  for (int kc = 0; kc < KRANGE / 4; ++kc) {   // 128 chunks of 4 k
    float4 wv[TM];
#pragma unroll
    for (int r = 0; r < TM; ++r)
      wv[r] = ((const float4*)zbuf[r])[wb / 4 + kc];   // broadcast read
#pragma unroll
    for (int j = 0; j < 4; ++j) {
      const int k = wb + kc * 4 + j;
      const float2 vv = *(const float2*)&Vb[(size_t)k * DDIM + lane * 2];
#pragma unroll
      for (int r = 0; r < TM; ++r) {
        const float wj = (j == 0) ? wv[r].x : (j == 1) ? wv[r].y
                       : (j == 2) ? wv[r].z : wv[r].w;
        o[r][0] = fmaf(wj, vv.x, o[r][0]);
        o[r][1] = fmaf(wj, vv.y, o[r][1]);
      }
    }
  }

  // ---------- cross-wave reduce via each wave's dead score slab -------------
  // wave w's slab (zbuf[*][wb..wb+512)) is read only by wave w in phase 4,
  // so it can write partials there without a barrier.
  float* base = (float*)zbuf;
  // partial layout: i in [0,1024): addr = (i>>9)*SS + wb + (i&511)
#pragma unroll
  for (int r = 0; r < TM; ++r) {
#pragma unroll
    for (int c2 = 0; c2 < 2; ++c2) {
      const int i = r * DDIM + lane * 2 + c2;
      base[(i >> 9) * SS + wb + (i & 511)] = o[r][c2];
    }
  }
  __syncthreads();

  {
    const int i = tid * 4;                      // 4 output elems per thread
    float4 s = make_float4(0.f, 0.f, 0.f, 0.f);
#pragma unroll
    for (int w = 0; w < 4; ++w) {
      const float4 pv = *(const float4*)&base[(i >> 9) * SS + w * KRANGE + (i & 511)];
      s.x += pv.x; s.y += pv.y; s.z += pv.z; s.w += pv.w;
    }
    *(float4*)&Ob[i] = s;
  }
}

extern "C" void kernel_launch(void* const* d_in, const int* in_sizes, int n_in,
                              void* d_out, int out_size, void* d_ws, size_t ws_size,
                              hipStream_t stream) {
  const float* Q = (const float*)d_in[0];
  const float* K = (const float*)d_in[1];
  const float* V = (const float*)d_in[2];
  float* out = (float*)d_out;

  const int grid = BB * (SS / TM);          // 2048 blocks
  hipLaunchKernelGGL(attn_fused, dim3(grid), dim3(256), 0, stream, Q, K, V, out);
}

// Round 5
// 271.732 us; speedup vs baseline: 5.6213x; 2.1677x over previous
//
#include <hip/hip_runtime.h>

#define BB 8
#define SS 2048
#define DD 128
#define KTILES 32          // 32 K-tiles of 64 rows

typedef short bf16x8 __attribute__((ext_vector_type(8)));
typedef float f32x4 __attribute__((ext_vector_type(4)));

template <int I> struct IC { static constexpr int value = I; };
template <int I, int N, typename F>
__device__ __forceinline__ void sfor(F&& f) {
  if constexpr (I < N) { f(IC<I>{}); sfor<I + 1, N>((F&&)f); }
}

__device__ __forceinline__ unsigned short f2bf(float x) {
  __bf16 b = (__bf16)x;
  return __builtin_bit_cast(unsigned short, b);
}
__device__ __forceinline__ float bf2f(unsigned short u) {
  return __uint_as_float(((unsigned)u) << 16);
}

// ---------------- V -> bf16 prep (once, into d_ws) ----------------
__global__ __launch_bounds__(256)
void v2bf(const float* __restrict__ V, unsigned short* __restrict__ Vb) {
  const size_t i = ((size_t)blockIdx.x * 256 + threadIdx.x) * 4;
  float4 v = *(const float4*)&V[i];
  ushort4 u;
  u.x = f2bf(v.x); u.y = f2bf(v.y); u.z = f2bf(v.z); u.w = f2bf(v.w);
  *(ushort4*)&Vb[i] = u;
}

// ---------------- fused entmax attention, MFMA ----------------
struct PhaseA {  // K/Q staged as split bf16, row stride 136 (=17x16B) kills 16-way conflicts
  unsigned short qhi[16][136], qlo[16][136];
  unsigned short khi[64][136], klo[64][136];
};
union SharedU { PhaseA a; unsigned short W[16][2048]; };  // phases strictly ordered by barriers

__global__ __launch_bounds__(256) __attribute__((amdgpu_waves_per_eu(2, 2)))
void attn(const float* __restrict__ Q, const float* __restrict__ K,
          const unsigned short* __restrict__ Vbf, float* __restrict__ Out) {
  __shared__ SharedU sh;
  __shared__ float exM[4][16];   // per-wave row-max partials
  __shared__ float exZ[4][16];   // per-wave Z partials (slow path only)
  __shared__ float rbuf[16][64]; // compacted support values per row
  __shared__ int   rcnt[16];
  __shared__ float tauB[16], ZB[16];
  __shared__ int   flagv;

  const int tid  = threadIdx.x;
  const int lane = tid & 63;
  const int wid  = __builtin_amdgcn_readfirstlane(tid >> 6);  // 0..3
  const int m16  = lane & 15;
  const int quad = lane >> 4;
  const int b    = blockIdx.x & 7;       // batch -> XCD pinning
  const int qt   = blockIdx.x >> 3;      // 0..127

  const float* Qb = Q + (size_t)(b * SS + qt * 16) * DD;
  const float* Kb = K + (size_t)b * SS * DD;
  const unsigned short* Vb = Vbf + (size_t)b * SS * DD;
  float* Ob = Out + (size_t)(b * SS + qt * 16) * DD;

  if (tid < 16) rcnt[tid] = 0;
  if (tid == 0) flagv = 0;

  // ---- stage Q (x0.5 folded = (alpha-1)), split hi/lo bf16 ----
  {
    const int m = tid >> 4, c0 = (tid & 15) * 8;
    float4 x = *(const float4*)&Qb[m * DD + c0];
    float4 y = *(const float4*)&Qb[m * DD + c0 + 4];
    bf16x8 h, l;
#pragma unroll
    for (int e = 0; e < 8; ++e) {
      const float4 vv = (e < 4) ? x : y;
      const int c = e & 3;
      float v = 0.5f * (c == 0 ? vv.x : c == 1 ? vv.y : c == 2 ? vv.z : vv.w);
      unsigned short hu = f2bf(v);
      h[e] = (short)hu;
      l[e] = (short)f2bf(v - bf2f(hu));
    }
    *(bf16x8*)&sh.a.qhi[m][c0] = h;
    *(bf16x8*)&sh.a.qlo[m][c0] = l;
  }

  // ---- phase 1: z = (0.5 Q) K^T via split-bf16 MFMA ----
  f32x4 acc[KTILES];
  sfor<0, KTILES>([&](auto Tc) { acc[Tc.value] = f32x4{0.f, 0.f, 0.f, 0.f}; });
  bf16x8 ahi[4], alo[4];

  const int krow = tid >> 2, kc0 = (tid & 3) * 32;
  sfor<0, KTILES>([&](auto Tc) {
    constexpr int T = Tc.value;
    float4 kv[8];
    {
      const float4* Ksrc = (const float4*)(Kb + (size_t)(64 * T + krow) * DD + kc0);
#pragma unroll
      for (int i = 0; i < 8; ++i) kv[i] = Ksrc[i];
    }
    __syncthreads();   // WAR: prior tile's B-frag reads done
#pragma unroll
    for (int g = 0; g < 4; ++g) {
      bf16x8 h, l;
#pragma unroll
      for (int e = 0; e < 8; ++e) {
        const float4 vv = kv[2 * g + (e >> 2)];
        const int c = e & 3;
        float v = (c == 0 ? vv.x : c == 1 ? vv.y : c == 2 ? vv.z : vv.w);
        unsigned short hu = f2bf(v);
        h[e] = (short)hu;
        l[e] = (short)f2bf(v - bf2f(hu));
      }
      *(bf16x8*)&sh.a.khi[krow][kc0 + 8 * g] = h;
      *(bf16x8*)&sh.a.klo[krow][kc0 + 8 * g] = l;
    }
    __syncthreads();   // staged tile visible
    if constexpr (T == 0) {
#pragma unroll
      for (int s = 0; s < 4; ++s) {
        ahi[s] = *(const bf16x8*)&sh.a.qhi[m16][32 * s + 8 * quad];
        alo[s] = *(const bf16x8*)&sh.a.qlo[m16][32 * s + 8 * quad];
      }
    }
    const int brow = 16 * wid + m16;
    f32x4 c = acc[T];
#pragma unroll
    for (int s = 0; s < 4; ++s) {
      bf16x8 bh = *(const bf16x8*)&sh.a.khi[brow][32 * s + 8 * quad];
      bf16x8 bl = *(const bf16x8*)&sh.a.klo[brow][32 * s + 8 * quad];
      c = __builtin_amdgcn_mfma_f32_16x16x32_bf16(ahi[s], bh, c, 0, 0, 0);
      c = __builtin_amdgcn_mfma_f32_16x16x32_bf16(alo[s], bh, c, 0, 0, 0);
      c = __builtin_amdgcn_mfma_f32_16x16x32_bf16(ahi[s], bl, c, 0, 0, 0);
    }
    acc[T] = c;
  });
  // lane holds z[row=4*quad+j][col=64*T+16*wid+m16]

  // ---- row max ----
  float mx[4] = {-1e38f, -1e38f, -1e38f, -1e38f};
  sfor<0, KTILES>([&](auto Tc) {
#pragma unroll
    for (int j = 0; j < 4; ++j) mx[j] = fmaxf(mx[j], acc[Tc.value][j]);
  });
#pragma unroll
  for (int j = 0; j < 4; ++j)
#pragma unroll
    for (int s = 1; s <= 8; s <<= 1) mx[j] = fmaxf(mx[j], __shfl_xor(mx[j], s));
  if (m16 == 0) {
    float4 t; t.x = mx[0]; t.y = mx[1]; t.z = mx[2]; t.w = mx[3];
    *(float4*)&exM[wid][4 * quad] = t;
  }
  __syncthreads();
  float M4[4] = {-1e38f, -1e38f, -1e38f, -1e38f};
#pragma unroll
  for (int w = 0; w < 4; ++w) {
    float4 t = *(const float4*)&exM[w][4 * quad];
    M4[0] = fmaxf(M4[0], t.x); M4[1] = fmaxf(M4[1], t.y);
    M4[2] = fmaxf(M4[2], t.z); M4[3] = fmaxf(M4[3], t.w);
  }

  // ---- compact support (z > zmax-1; tau >= zmax-1 always) ----
  float cv0[4], cv1[4], cv2[4], cv3[4];
  int cnt[4];
  bool ov = false;
#pragma unroll
  for (int j = 0; j < 4; ++j) { cv0[j] = cv1[j] = cv2[j] = cv3[j] = -1e38f; cnt[j] = 0; }
  sfor<0, KTILES>([&](auto Tc) {
#pragma unroll
    for (int j = 0; j < 4; ++j) {
      float v = acc[Tc.value][j];
      bool act = v > (M4[j] - 1.0f);
      cnt[j] += act ? 1 : 0;
      float x = act ? v : -1e38f;
      float m0 = fmaxf(cv0[j], x); x = fminf(cv0[j], x); cv0[j] = m0;
      float m1 = fmaxf(cv1[j], x); x = fminf(cv1[j], x); cv1[j] = m1;
      float m2 = fmaxf(cv2[j], x); x = fminf(cv2[j], x); cv2[j] = m2;
      cv3[j] = fmaxf(cv3[j], x);
    }
  });
#pragma unroll
  for (int j = 0; j < 4; ++j) {
    if (cnt[j] > 4) ov = true;
    const int row = 4 * quad + j;
    float vals[4] = {cv0[j], cv1[j], cv2[j], cv3[j]};
#pragma unroll
    for (int i = 0; i < 4; ++i) {
      if (vals[i] > -1e37f) {
        int idx = atomicAdd(&rcnt[row], 1);
        if (idx < 64) rbuf[row][idx] = vals[i];
        else ov = true;
      }
    }
  }
  if (ov) atomicOr(&flagv, 1);
  __syncthreads();

  // ---- bisection (fast: support lists, no barriers; slow: exact fallback) ----
  if (flagv == 0) {
    const int row = lane >> 2;
    float Mr = -1e38f;
#pragma unroll
    for (int w = 0; w < 4; ++w) Mr = fmaxf(Mr, exM[w][row]);
    float tmn = Mr - 1.0f, tmx = Mr - 0.022097086912079608f;
    float tau = 0.5f * (tmn + tmx), Zr = 0.f;
    const int n = rcnt[row];
    for (int it = 0; it < 100; ++it) {
      tau = 0.5f * (tmn + tmx);
      float zp = 0.f;
      for (int i = (lane & 3); i < n; i += 4) {
        float tt = fmaxf(rbuf[row][i] - tau, 0.f);
        zp = fmaf(tt, tt, zp);
      }
      zp += __shfl_xor(zp, 1);
      zp += __shfl_xor(zp, 2);
      Zr = zp;
      float nmin = (zp >= 1.f) ? tau : tmn;
      float nmax = (zp >= 1.f) ? tmx : tau;
      bool ch = (nmin != tmn) || (nmax != tmx);
      tmn = nmin; tmx = nmax;
      if (!__any(ch)) break;   // fixed point: faithful to 100 iters
    }
    if (wid == 0 && (lane & 3) == 0) { tauB[row] = tau; ZB[row] = Zr; }
  } else {
    float tmn[4], tmx[4], tau4[4], Z4[4];
#pragma unroll
    for (int j = 0; j < 4; ++j) {
      tmn[j] = M4[j] - 1.0f; tmx[j] = M4[j] - 0.022097086912079608f;
      tau4[j] = 0.5f * (tmn[j] + tmx[j]); Z4[j] = 0.f;
    }
    for (int it = 0; it < 100; ++it) {
      float zp[4] = {0.f, 0.f, 0.f, 0.f};
#pragma unroll
      for (int j = 0; j < 4; ++j) tau4[j] = 0.5f * (tmn[j] + tmx[j]);
      sfor<0, KTILES>([&](auto Tc) {
#pragma unroll
        for (int j = 0; j < 4; ++j) {
          float tt = fmaxf(acc[Tc.value][j] - tau4[j], 0.f);
          zp[j] = fmaf(tt, tt, zp[j]);
        }
      });
#pragma unroll
      for (int j = 0; j < 4; ++j)
#pragma unroll
        for (int s = 1; s <= 8; s <<= 1) zp[j] += __shfl_xor(zp[j], s);
      if (m16 == 0) {
        float4 t; t.x = zp[0]; t.y = zp[1]; t.z = zp[2]; t.w = zp[3];
        *(float4*)&exZ[wid][4 * quad] = t;
      }
      __syncthreads();
      float Zf[4] = {0.f, 0.f, 0.f, 0.f};
#pragma unroll
      for (int w = 0; w < 4; ++w) {
        float4 t = *(const float4*)&exZ[w][4 * quad];
        Zf[0] += t.x; Zf[1] += t.y; Zf[2] += t.z; Zf[3] += t.w;
      }
      __syncthreads();
      bool ch = false;
#pragma unroll
      for (int j = 0; j < 4; ++j) {
        float nmin = (Zf[j] >= 1.f) ? tau4[j] : tmn[j];
        float nmax = (Zf[j] >= 1.f) ? tmx[j] : tau4[j];
        ch = ch || (nmin != tmn[j]) || (nmax != tmx[j]);
        tmn[j] = nmin; tmx[j] = nmax; Z4[j] = Zf[j];
      }
      if (!__any(ch)) break;
    }
    if (wid == 0 && m16 == 0) {
#pragma unroll
      for (int j = 0; j < 4; ++j) { tauB[4 * quad + j] = tau4[j]; ZB[4 * quad + j] = Z4[j]; }
    }
  }
  __syncthreads();

  // ---- weights -> bf16 into LDS (XOR-granule swizzle for A-frag reads) ----
  float tauR[4], ZR[4];
  {
    float4 t = *(const float4*)&tauB[4 * quad];
    float4 z = *(const float4*)&ZB[4 * quad];
    tauR[0] = t.x; tauR[1] = t.y; tauR[2] = t.z; tauR[3] = t.w;
    ZR[0] = z.x; ZR[1] = z.y; ZR[2] = z.z; ZR[3] = z.w;
  }
  float iz[4];
#pragma unroll
  for (int j = 0; j < 4; ++j) iz[j] = 1.0f / ZR[j];
  sfor<0, KTILES>([&](auto Tc) {
    constexpr int T = Tc.value;
    const int col = 64 * T + 16 * wid + m16;
    const int g = col >> 3;
#pragma unroll
    for (int j = 0; j < 4; ++j) {
      const int row = 4 * quad + j;
      float tt = fmaxf(acc[T][j] - tauR[j], 0.f);
      sh.W[row][(g ^ (row & 7)) * 8 + (col & 7)] = f2bf(tt * tt * iz[j]);
    }
  });
  __syncthreads();

  // ---- phase 4: O = W @ V via MFMA (W bf16 A-frags from LDS, V bf16 gathers) ----
  f32x4 o0 = {0.f, 0.f, 0.f, 0.f}, o1 = {0.f, 0.f, 0.f, 0.f};
  const int d0 = 32 * wid;
  const int vbase = (8 * quad) * DD + d0 + m16;
  for (int s = 0; s < 64; ++s) {
    const int g = 4 * s + quad;
    bf16x8 a = *(const bf16x8*)&sh.W[m16][(g ^ (m16 & 7)) * 8];
    bf16x8 b0, b1;
#pragma unroll
    for (int j = 0; j < 8; ++j) {
      b0[j] = (short)Vb[vbase + 4096 * s + 128 * j];
      b1[j] = (short)Vb[vbase + 4096 * s + 128 * j + 16];
    }
    o0 = __builtin_amdgcn_mfma_f32_16x16x32_bf16(a, b0, o0, 0, 0, 0);
    o1 = __builtin_amdgcn_mfma_f32_16x16x32_bf16(a, b1, o1, 0, 0, 0);
  }
#pragma unroll
  for (int j = 0; j < 4; ++j) {
    const int row = 4 * quad + j;
    Ob[row * DD + d0 + m16]      = o0[j];
    Ob[row * DD + d0 + 16 + m16] = o1[j];
  }
}

extern "C" void kernel_launch(void* const* d_in, const int* in_sizes, int n_in,
                              void* d_out, int out_size, void* d_ws, size_t ws_size,
                              hipStream_t stream) {
  const float* Q = (const float*)d_in[0];
  const float* K = (const float*)d_in[1];
  const float* V = (const float*)d_in[2];
  float* out = (float*)d_out;
  unsigned short* Vbf = (unsigned short*)d_ws;   // 4 MiB bf16 V

  hipLaunchKernelGGL(v2bf, dim3(BB * SS * DD / 1024), dim3(256), 0, stream, V, Vbf);
  hipLaunchKernelGGL(attn, dim3(BB * (SS / 16)), dim3(256), 0, stream, Q, K, Vbf, out);
}

// Round 7
// 204.359 us; speedup vs baseline: 7.4746x; 1.3297x over previous
//
#include <hip/hip_runtime.h>

#define BB 8
#define SS 2048
#define DD 128
#define ROWS 16            // q rows per block
#define NW 8               // waves per block (512 threads)
#define CTW 16             // col-tiles (of 16) per wave -> 256 cols/wave

typedef short bf16x8 __attribute__((ext_vector_type(8)));
typedef float f32x4 __attribute__((ext_vector_type(4)));

template <int I> struct IC { static constexpr int value = I; };
template <int I, int N, typename F>
__device__ __forceinline__ void sfor(F&& f) {
  if constexpr (I < N) { f(IC<I>{}); sfor<I + 1, N>((F&&)f); }
}

__device__ __forceinline__ short f2bf(float x) {
  return __builtin_bit_cast(short, (__bf16)x);
}
__device__ __forceinline__ float bf2f(short u) {
  return __uint_as_float(((unsigned)(unsigned short)u) << 16);
}

// ---- prep: K split into hi/lo bf16, packed in MFMA B-fragment order ----
// Frag (b,ct,s,lane): lane(quad,m16) holds K[b][ct*16+m16][s*32+quad*8 .. +8]
// (identical per-lane layout to R5's LDS-staged B-frags, which passed.)
__global__ __launch_bounds__(256)
void ksplit(const float* __restrict__ K, short* __restrict__ Khi,
            short* __restrict__ Klo) {
  const int lin  = blockIdx.x * 256 + threadIdx.x;   // 262144 frags
  const int b    = lin >> 15;
  const int rem  = lin & 32767;
  const int ct   = rem >> 8;
  const int s    = (rem >> 6) & 3;
  const int lane = rem & 63;
  const int quad = lane >> 4, m16 = lane & 15;
  const float* src = K + ((size_t)(b * SS + ct * 16 + m16) * DD + s * 32 + quad * 8);
  const float4 v0 = *(const float4*)src;
  const float4 v1 = *(const float4*)(src + 4);
  const float f[8] = {v0.x, v0.y, v0.z, v0.w, v1.x, v1.y, v1.z, v1.w};
  bf16x8 h, l;
#pragma unroll
  for (int e = 0; e < 8; ++e) {
    h[e] = f2bf(f[e]);
    l[e] = f2bf(f[e] - bf2f(h[e]));
  }
  *(bf16x8*)(Khi + (size_t)lin * 8) = h;
  *(bf16x8*)(Klo + (size_t)lin * 8) = l;
}

// ---- fused entmax attention (R5 semantics, barrier-free phase 1) ----
__global__ __launch_bounds__(512) __attribute__((amdgpu_waves_per_eu(3, 4)))
void attn(const float* __restrict__ Q, const short* __restrict__ Khi,
          const short* __restrict__ Klo, const float* __restrict__ V,
          float* __restrict__ Out) {
  __shared__ unsigned short W[ROWS][2048];     // 64 KB weights (bf16, swizzled)
  __shared__ unsigned short Qs[2][ROWS][136];  // split-bf16 Q (0.5 folded)
  __shared__ float rbuf[ROWS][64];             // support VALUES per row
  __shared__ float exM[NW][ROWS];
  __shared__ float exZ[NW][ROWS];              // slow path only
  __shared__ int   rcnt[ROWS];
  __shared__ float tauB[ROWS], ZB[ROWS];
  __shared__ int   flagv;

  const int tid  = threadIdx.x;
  const int lane = tid & 63;
  const int wid  = __builtin_amdgcn_readfirstlane(tid >> 6);  // 0..7
  const int quad = lane >> 4, m16 = lane & 15;
  const int b    = blockIdx.x & 7;             // batch -> XCD pinning
  const int qt   = blockIdx.x >> 3;            // 0..127

  const float* Qb = Q + (size_t)(b * SS + qt * ROWS) * DD;
  const float* Vb = V + (size_t)b * SS * DD;
  float*       Ob = Out + (size_t)(b * SS + qt * ROWS) * DD;
  const short* KHb = Khi + (size_t)b * SS * DD;
  const short* KLb = Klo + (size_t)b * SS * DD;

  if (tid < ROWS) rcnt[tid] = 0;
  if (tid == ROWS) flagv = 0;

  // ---- stage Q once: 0.5*q split hi+lo bf16 (A-operand layout, as R5) ----
  {
    const int row = tid >> 5, d = (tid & 31) * 4;
    const float4 v = *(const float4*)&Qb[row * DD + d];
    const float f[4] = {v.x, v.y, v.z, v.w};
    ushort4 h, l;
    unsigned short hh[4], ll[4];
#pragma unroll
    for (int e = 0; e < 4; ++e) {
      const float x = 0.5f * f[e];
      hh[e] = (unsigned short)f2bf(x);
      ll[e] = (unsigned short)f2bf(x - bf2f((short)hh[e]));
    }
    h.x = hh[0]; h.y = hh[1]; h.z = hh[2]; h.w = hh[3];
    l.x = ll[0]; l.y = ll[1]; l.z = ll[2]; l.w = ll[3];
    *(ushort4*)&Qs[0][row][d] = h;
    *(ushort4*)&Qs[1][row][d] = l;
  }
  __syncthreads();

  bf16x8 qh[4], ql[4];
#pragma unroll
  for (int s = 0; s < 4; ++s) {
    qh[s] = *(const bf16x8*)&Qs[0][m16][s * 32 + quad * 8];
    ql[s] = *(const bf16x8*)&Qs[1][m16][s * 32 + quad * 8];
  }

  // ---- phase 1: z2 = (0.5Q)K^T, 3-term split-bf16 (R5's), B from global ----
  f32x4 acc[CTW];
  sfor<0, CTW>([&](auto ic) {
    constexpr int i = ic.value;
    const int ct = wid * CTW + i;
    const short* bh0 = KHb + ((size_t)ct << 11) + lane * 8;
    const short* bl0 = KLb + ((size_t)ct << 11) + lane * 8;
    f32x4 c = {0.f, 0.f, 0.f, 0.f};
    sfor<0, 4>([&](auto sc) {
      constexpr int s = sc.value;
      const bf16x8 bh = *(const bf16x8*)(bh0 + (s << 9));
      const bf16x8 bl = *(const bf16x8*)(bl0 + (s << 9));
      c = __builtin_amdgcn_mfma_f32_16x16x32_bf16(qh[s], bh, c, 0, 0, 0);
      c = __builtin_amdgcn_mfma_f32_16x16x32_bf16(ql[s], bh, c, 0, 0, 0);
      c = __builtin_amdgcn_mfma_f32_16x16x32_bf16(qh[s], bl, c, 0, 0, 0);
    });
    acc[i] = c;
  });
  // lane holds z2[row=4*quad+j][col = wid*256 + i*16 + m16]

  // ---- row max ----
  float mx[4] = {-1e38f, -1e38f, -1e38f, -1e38f};
  sfor<0, CTW>([&](auto ic) {
#pragma unroll
    for (int j = 0; j < 4; ++j) mx[j] = fmaxf(mx[j], acc[ic.value][j]);
  });
#pragma unroll
  for (int j = 0; j < 4; ++j)
#pragma unroll
    for (int s = 1; s <= 8; s <<= 1) mx[j] = fmaxf(mx[j], __shfl_xor(mx[j], s));
  if (m16 == 0) {
#pragma unroll
    for (int j = 0; j < 4; ++j) exM[wid][4 * quad + j] = mx[j];
  }
  __syncthreads();
  float M4[4];
#pragma unroll
  for (int j = 0; j < 4; ++j) {
    float m = -1e38f;
#pragma unroll
    for (int w = 0; w < NW; ++w) m = fmaxf(m, exM[w][4 * quad + j]);
    M4[j] = m;
  }

  // ---- compact support VALUES (z2 > max2 - 1; exact on the z2 array) ----
  float cv0[4], cv1[4], cv2[4], cv3[4];
  int cnt[4];
  bool ov = false;
#pragma unroll
  for (int j = 0; j < 4; ++j) { cv0[j] = cv1[j] = cv2[j] = cv3[j] = -1e38f; cnt[j] = 0; }
  sfor<0, CTW>([&](auto ic) {
#pragma unroll
    for (int j = 0; j < 4; ++j) {
      float v = acc[ic.value][j];
      bool act = v > (M4[j] - 1.0f);
      cnt[j] += act ? 1 : 0;
      float x = act ? v : -1e38f;
      float m0 = fmaxf(cv0[j], x); x = fminf(cv0[j], x); cv0[j] = m0;
      float m1 = fmaxf(cv1[j], x); x = fminf(cv1[j], x); cv1[j] = m1;
      float m2 = fmaxf(cv2[j], x); x = fminf(cv2[j], x); cv2[j] = m2;
      cv3[j] = fmaxf(cv3[j], x);
    }
  });
#pragma unroll
  for (int j = 0; j < 4; ++j) {
    if (cnt[j] > 4) ov = true;
    const int row = 4 * quad + j;
    float vals[4] = {cv0[j], cv1[j], cv2[j], cv3[j]};
#pragma unroll
    for (int i = 0; i < 4; ++i) {
      if (vals[i] > -1e37f) {
        int idx = atomicAdd(&rcnt[row], 1);
        if (idx < 64) rbuf[row][idx] = vals[i];
        else ov = true;
      }
    }
  }
  if (ov) atomicOr(&flagv, 1);
  __syncthreads();

  // ---- bisection (fast: support lists; slow: full z2, faithful) ----
  if (flagv == 0) {
    const int row = lane >> 2;
    float Mr = -1e38f;
#pragma unroll
    for (int w = 0; w < NW; ++w) Mr = fmaxf(Mr, exM[w][row]);
    float tmn = Mr - 1.0f, tmx = Mr - 0.022097086912079608f;  // S^(1-alpha)
    float tau = 0.5f * (tmn + tmx), Zr = 0.f;
    const int n = rcnt[row];
    for (int it = 0; it < 100; ++it) {
      tau = 0.5f * (tmn + tmx);
      float zp = 0.f;
      for (int i = (lane & 3); i < n; i += 4) {
        float tt = fmaxf(rbuf[row][i] - tau, 0.f);
        zp = fmaf(tt, tt, zp);
      }
      zp += __shfl_xor(zp, 1);
      zp += __shfl_xor(zp, 2);
      Zr = zp;
      float nmn = (zp >= 1.f) ? tau : tmn;
      float nmx = (zp >= 1.f) ? tmx : tau;
      bool ch = (nmn != tmn) || (nmx != tmx);
      tmn = nmn; tmx = nmx;
      if (!__any(ch)) break;   // fixed point: faithful to 100 iters
    }
    if (wid == 0 && (lane & 3) == 0) { tauB[row] = tau; ZB[row] = Zr; }
  } else {
    float tmn4[4], tmx4[4], tau4[4], Z4[4];
#pragma unroll
    for (int j = 0; j < 4; ++j) {
      tmn4[j] = M4[j] - 1.0f; tmx4[j] = M4[j] - 0.022097086912079608f;
      tau4[j] = 0.5f * (tmn4[j] + tmx4[j]); Z4[j] = 0.f;
    }
    for (int it = 0; it < 100; ++it) {
      float zp[4] = {0.f, 0.f, 0.f, 0.f};
#pragma unroll
      for (int j = 0; j < 4; ++j) tau4[j] = 0.5f * (tmn4[j] + tmx4[j]);
      sfor<0, CTW>([&](auto ic) {
#pragma unroll
        for (int j = 0; j < 4; ++j) {
          const float tt = fmaxf(acc[ic.value][j] - tau4[j], 0.f);
          zp[j] = fmaf(tt, tt, zp[j]);
        }
      });
#pragma unroll
      for (int j = 0; j < 4; ++j)
#pragma unroll
        for (int s = 1; s <= 8; s <<= 1) zp[j] += __shfl_xor(zp[j], s);
      if (m16 == 0) {
#pragma unroll
        for (int j = 0; j < 4; ++j) exZ[wid][4 * quad + j] = zp[j];
      }
      __syncthreads();
      bool ch = false;
#pragma unroll
      for (int j = 0; j < 4; ++j) {
        float Zf = 0.f;
#pragma unroll
        for (int w = 0; w < NW; ++w) Zf += exZ[w][4 * quad + j];
        Z4[j] = Zf;
        const float nmn = (Zf >= 1.f) ? tau4[j] : tmn4[j];
        const float nmx = (Zf >= 1.f) ? tmx4[j] : tau4[j];
        ch = ch || (nmn != tmn4[j]) || (nmx != tmx4[j]);
        tmn4[j] = nmn; tmx4[j] = nmx;
      }
      __syncthreads();
      if (!ch) break;          // block-uniform (Zf uniform) -> barrier-safe
    }
    if (wid == 0 && m16 == 0) {
#pragma unroll
      for (int j = 0; j < 4; ++j) { tauB[4 * quad + j] = tau4[j]; ZB[4 * quad + j] = Z4[j]; }
    }
  }
  __syncthreads();

  // ---- phase 3: weights from FULL z2 array -> bf16 W (swizzled), as R5 ----
  float tauR[4], izR[4];
#pragma unroll
  for (int j = 0; j < 4; ++j) {
    tauR[j] = tauB[4 * quad + j];
    izR[j]  = 1.0f / ZB[4 * quad + j];
  }
  sfor<0, CTW>([&](auto ic) {
    constexpr int i = ic.value;
    const int col = wid * 256 + i * 16 + m16;
    const int g = col >> 3;
#pragma unroll
    for (int j = 0; j < 4; ++j) {
      const int row = 4 * quad + j;
      const float tt = fmaxf(acc[i][j] - tauR[j], 0.f);
      W[row][(g ^ (row & 7)) * 8 + (col & 7)] = (unsigned short)f2bf(tt * tt * izR[j]);
    }
  });
  __syncthreads();

  // ---- phase 4: O = W @ V via MFMA; wave owns d-slice [16*wid, +16) ----
  f32x4 o = {0.f, 0.f, 0.f, 0.f};
  const int d0 = 16 * wid;
  const int vbase = quad * 1024 + d0 + m16;   // (quad*8)*DD + d0 + m16
  for (int s = 0; s < 64; ++s) {
    const int g = 4 * s + quad;
    const bf16x8 a = *(const bf16x8*)&W[m16][(g ^ (m16 & 7)) * 8];
    bf16x8 bv;
#pragma unroll
    for (int j = 0; j < 8; ++j)
      bv[j] = f2bf(Vb[vbase + 4096 * s + 128 * j]);
    o = __builtin_amdgcn_mfma_f32_16x16x32_bf16(a, bv, o, 0, 0, 0);
  }
#pragma unroll
  for (int j = 0; j < 4; ++j)
    Ob[(4 * quad + j) * DD + d0 + m16] = o[j];
}

extern "C" void kernel_launch(void* const* d_in, const int* in_sizes, int n_in,
                              void* d_out, int out_size, void* d_ws, size_t ws_size,
                              hipStream_t stream) {
  const float* Q = (const float*)d_in[0];
  const float* K = (const float*)d_in[1];
  const float* V = (const float*)d_in[2];
  float* out = (float*)d_out;
  short* Khi = (short*)d_ws;                       // 4 MiB
  short* Klo = Khi + (size_t)BB * SS * DD;         // 4 MiB

  hipLaunchKernelGGL(ksplit, dim3(BB * SS * DD / (256 * 8)), dim3(256), 0, stream,
                     K, Khi, Klo);
  hipLaunchKernelGGL(attn, dim3(BB * (SS / ROWS)), dim3(512), 0, stream,
                     Q, Khi, Klo, V, out);
}

// Round 8
// 168.849 us; speedup vs baseline: 9.0465x; 1.2103x over previous
//
#include <hip/hip_runtime.h>

#define BB 8
#define SS 2048
#define DD 128
#define ROWS 16            // q rows per block
#define NW 8               // waves per block (512 threads)
#define CTW 16             // col-tiles (of 16) per wave -> 256 cols/wave

typedef short bf16x8 __attribute__((ext_vector_type(8)));
typedef float f32x4 __attribute__((ext_vector_type(4)));

template <int I> struct IC { static constexpr int value = I; };
template <int I, int N, typename F>
__device__ __forceinline__ void sfor(F&& f) {
  if constexpr (I < N) { f(IC<I>{}); sfor<I + 1, N>((F&&)f); }
}

__device__ __forceinline__ short f2bf(float x) {
  return __builtin_bit_cast(short, (__bf16)x);
}
__device__ __forceinline__ float bf2f(short u) {
  return __uint_as_float(((unsigned)(unsigned short)u) << 16);
}

// ---- prep: K split into hi/lo bf16, packed in MFMA B-fragment order ----
// Frag (b,ct,s,lane): lane(quad,m16) holds K[b][ct*16+m16][s*32+quad*8 .. +8]
__global__ __launch_bounds__(256)
void ksplit(const float* __restrict__ K, short* __restrict__ Khi,
            short* __restrict__ Klo) {
  const int lin  = blockIdx.x * 256 + threadIdx.x;   // 262144 frags
  const int b    = lin >> 15;
  const int rem  = lin & 32767;
  const int ct   = rem >> 8;
  const int s    = (rem >> 6) & 3;
  const int lane = rem & 63;
  const int quad = lane >> 4, m16 = lane & 15;
  const float* src = K + ((size_t)(b * SS + ct * 16 + m16) * DD + s * 32 + quad * 8);
  const float4 v0 = *(const float4*)src;
  const float4 v1 = *(const float4*)(src + 4);
  const float f[8] = {v0.x, v0.y, v0.z, v0.w, v1.x, v1.y, v1.z, v1.w};
  bf16x8 h, l;
#pragma unroll
  for (int e = 0; e < 8; ++e) {
    h[e] = f2bf(f[e]);
    l[e] = f2bf(f[e] - bf2f(h[e]));
  }
  *(bf16x8*)(Khi + (size_t)lin * 8) = h;
  *(bf16x8*)(Klo + (size_t)lin * 8) = l;
}

// ---- fused entmax attention: R7's z2/tau/Z + exact-sparse fp32 output ----
__global__ __launch_bounds__(512) __attribute__((amdgpu_waves_per_eu(3, 4)))
void attn(const float* __restrict__ Q, const short* __restrict__ Khi,
          const short* __restrict__ Klo, const float* __restrict__ V,
          float* __restrict__ Out) {
  __shared__ unsigned short Qs[2][ROWS][136];  // split-bf16 Q (0.5 folded)
  __shared__ float rbuf[ROWS][64];             // candidate VALUES per row
  __shared__ float exM[NW][ROWS];
  __shared__ float exZ[NW][ROWS];              // slow bisection only
  __shared__ int   rcnt[ROWS];
  __shared__ float tauB[ROWS], ZB[ROWS];
  __shared__ int   flagv;
  __shared__ int   scnt[ROWS];                 // support list (exact p > 0)
  __shared__ int   scol[ROWS][64];
  __shared__ float sp[ROWS][64];
  __shared__ int   oflag;
  __shared__ float obuf[ROWS][DD];             // dense fallback only

  const int tid  = threadIdx.x;
  const int lane = tid & 63;
  const int wid  = __builtin_amdgcn_readfirstlane(tid >> 6);  // 0..7
  const int quad = lane >> 4, m16 = lane & 15;
  const int b    = blockIdx.x & 7;             // batch -> XCD pinning
  const int qt   = blockIdx.x >> 3;            // 0..127

  const float* Qb = Q + (size_t)(b * SS + qt * ROWS) * DD;
  const float* Vb = V + (size_t)b * SS * DD;
  float*       Ob = Out + (size_t)(b * SS + qt * ROWS) * DD;
  const short* KHb = Khi + (size_t)b * SS * DD;
  const short* KLb = Klo + (size_t)b * SS * DD;

  if (tid < ROWS) { rcnt[tid] = 0; scnt[tid] = 0; }
  if (tid == ROWS) { flagv = 0; oflag = 0; }

  // ---- stage Q once: 0.5*q split hi+lo bf16 (A-operand layout) ----
  {
    const int row = tid >> 5, d = (tid & 31) * 4;
    const float4 v = *(const float4*)&Qb[row * DD + d];
    const float f[4] = {v.x, v.y, v.z, v.w};
    ushort4 h, l;
    unsigned short hh[4], ll[4];
#pragma unroll
    for (int e = 0; e < 4; ++e) {
      const float x = 0.5f * f[e];
      hh[e] = (unsigned short)f2bf(x);
      ll[e] = (unsigned short)f2bf(x - bf2f((short)hh[e]));
    }
    h.x = hh[0]; h.y = hh[1]; h.z = hh[2]; h.w = hh[3];
    l.x = ll[0]; l.y = ll[1]; l.z = ll[2]; l.w = ll[3];
    *(ushort4*)&Qs[0][row][d] = h;
    *(ushort4*)&Qs[1][row][d] = l;
  }
  __syncthreads();

  bf16x8 qh[4], ql[4];
#pragma unroll
  for (int s = 0; s < 4; ++s) {
    qh[s] = *(const bf16x8*)&Qs[0][m16][s * 32 + quad * 8];
    ql[s] = *(const bf16x8*)&Qs[1][m16][s * 32 + quad * 8];
  }

  // ---- phase 1: z2 = (0.5Q)K^T, 3-term split-bf16, B-frags from global ----
  f32x4 acc[CTW];
  sfor<0, CTW>([&](auto ic) {
    constexpr int i = ic.value;
    const int ct = wid * CTW + i;
    const short* bh0 = KHb + ((size_t)ct << 11) + lane * 8;
    const short* bl0 = KLb + ((size_t)ct << 11) + lane * 8;
    f32x4 c = {0.f, 0.f, 0.f, 0.f};
    sfor<0, 4>([&](auto sc) {
      constexpr int s = sc.value;
      const bf16x8 bh = *(const bf16x8*)(bh0 + (s << 9));
      const bf16x8 bl = *(const bf16x8*)(bl0 + (s << 9));
      c = __builtin_amdgcn_mfma_f32_16x16x32_bf16(qh[s], bh, c, 0, 0, 0);
      c = __builtin_amdgcn_mfma_f32_16x16x32_bf16(ql[s], bh, c, 0, 0, 0);
      c = __builtin_amdgcn_mfma_f32_16x16x32_bf16(qh[s], bl, c, 0, 0, 0);
    });
    acc[i] = c;
  });
  // lane holds z2[row=4*quad+j][col = wid*256 + i*16 + m16]

  // ---- row max ----
  float mx[4] = {-1e38f, -1e38f, -1e38f, -1e38f};
  sfor<0, CTW>([&](auto ic) {
#pragma unroll
    for (int j = 0; j < 4; ++j) mx[j] = fmaxf(mx[j], acc[ic.value][j]);
  });
#pragma unroll
  for (int j = 0; j < 4; ++j)
#pragma unroll
    for (int s = 1; s <= 8; s <<= 1) mx[j] = fmaxf(mx[j], __shfl_xor(mx[j], s));
  if (m16 == 0) {
#pragma unroll
    for (int j = 0; j < 4; ++j) exM[wid][4 * quad + j] = mx[j];
  }
  __syncthreads();
  float M4[4];
#pragma unroll
  for (int j = 0; j < 4; ++j) {
    float m = -1e38f;
#pragma unroll
    for (int w = 0; w < NW; ++w) m = fmaxf(m, exM[w][4 * quad + j]);
    M4[j] = m;
  }

  // ---- compact candidate VALUES (z2 > max2 - 1; tau >= max2 - 1 always) ----
  float cv0[4], cv1[4], cv2[4], cv3[4];
  int cnt[4];
  bool ov = false;
#pragma unroll
  for (int j = 0; j < 4; ++j) { cv0[j] = cv1[j] = cv2[j] = cv3[j] = -1e38f; cnt[j] = 0; }
  sfor<0, CTW>([&](auto ic) {
#pragma unroll
    for (int j = 0; j < 4; ++j) {
      float v = acc[ic.value][j];
      bool act = v > (M4[j] - 1.0f);
      cnt[j] += act ? 1 : 0;
      float x = act ? v : -1e38f;
      float m0 = fmaxf(cv0[j], x); x = fminf(cv0[j], x); cv0[j] = m0;
      float m1 = fmaxf(cv1[j], x); x = fminf(cv1[j], x); cv1[j] = m1;
      float m2 = fmaxf(cv2[j], x); x = fminf(cv2[j], x); cv2[j] = m2;
      cv3[j] = fmaxf(cv3[j], x);
    }
  });
#pragma unroll
  for (int j = 0; j < 4; ++j) {
    if (cnt[j] > 4) ov = true;
    const int row = 4 * quad + j;
    float vals[4] = {cv0[j], cv1[j], cv2[j], cv3[j]};
#pragma unroll
    for (int i = 0; i < 4; ++i) {
      if (vals[i] > -1e37f) {
        int idx = atomicAdd(&rcnt[row], 1);
        if (idx < 64) rbuf[row][idx] = vals[i];
        else ov = true;
      }
    }
  }
  if (ov) atomicOr(&flagv, 1);
  __syncthreads();

  // ---- bisection (fast: candidate lists; slow: full z2, faithful) ----
  if (flagv == 0) {
    const int row = lane >> 2;
    float Mr = -1e38f;
#pragma unroll
    for (int w = 0; w < NW; ++w) Mr = fmaxf(Mr, exM[w][row]);
    float tmn = Mr - 1.0f, tmx = Mr - 0.022097086912079608f;  // S^(1-alpha)
    float tau = 0.5f * (tmn + tmx), Zr = 0.f;
    const int n = rcnt[row];
    for (int it = 0; it < 100; ++it) {
      tau = 0.5f * (tmn + tmx);
      float zp = 0.f;
      for (int i = (lane & 3); i < n; i += 4) {
        float tt = fmaxf(rbuf[row][i] - tau, 0.f);
        zp = fmaf(tt, tt, zp);
      }
      zp += __shfl_xor(zp, 1);
      zp += __shfl_xor(zp, 2);
      Zr = zp;
      float nmn = (zp >= 1.f) ? tau : tmn;
      float nmx = (zp >= 1.f) ? tmx : tau;
      bool ch = (nmn != tmn) || (nmx != tmx);
      tmn = nmn; tmx = nmx;
      if (!__any(ch)) break;   // fixed point: faithful to 100 iters
    }
    if (wid == 0 && (lane & 3) == 0) { tauB[row] = tau; ZB[row] = Zr; }
  } else {
    float tmn4[4], tmx4[4], tau4[4], Z4[4];
#pragma unroll
    for (int j = 0; j < 4; ++j) {
      tmn4[j] = M4[j] - 1.0f; tmx4[j] = M4[j] - 0.022097086912079608f;
      tau4[j] = 0.5f * (tmn4[j] + tmx4[j]); Z4[j] = 0.f;
    }
    for (int it = 0; it < 100; ++it) {
      float zp[4] = {0.f, 0.f, 0.f, 0.f};
#pragma unroll
      for (int j = 0; j < 4; ++j) tau4[j] = 0.5f * (tmn4[j] + tmx4[j]);
      sfor<0, CTW>([&](auto ic) {
#pragma unroll
        for (int j = 0; j < 4; ++j) {
          const float tt = fmaxf(acc[ic.value][j] - tau4[j], 0.f);
          zp[j] = fmaf(tt, tt, zp[j]);
        }
      });
#pragma unroll
      for (int j = 0; j < 4; ++j)
#pragma unroll
        for (int s = 1; s <= 8; s <<= 1) zp[j] += __shfl_xor(zp[j], s);
      if (m16 == 0) {
#pragma unroll
        for (int j = 0; j < 4; ++j) exZ[wid][4 * quad + j] = zp[j];
      }
      __syncthreads();
      bool ch = false;
#pragma unroll
      for (int j = 0; j < 4; ++j) {
        float Zf = 0.f;
#pragma unroll
        for (int w = 0; w < NW; ++w) Zf += exZ[w][4 * quad + j];
        Z4[j] = Zf;
        const float nmn = (Zf >= 1.f) ? tau4[j] : tmn4[j];
        const float nmx = (Zf >= 1.f) ? tmx4[j] : tau4[j];
        ch = ch || (nmn != tmn4[j]) || (nmx != tmx4[j]);
        tmn4[j] = nmn; tmx4[j] = nmx;
      }
      __syncthreads();
      if (!ch) break;          // Zf block-uniform -> barrier-safe
    }
    if (wid == 0 && m16 == 0) {
#pragma unroll
      for (int j = 0; j < 4; ++j) { tauB[4 * quad + j] = tau4[j]; ZB[4 * quad + j] = Z4[j]; }
    }
  }
  __syncthreads();

  // ---- phase 3': exact support lists (col, fp32 weight) from full z2 ----
  float tauR[4], izR[4];
#pragma unroll
  for (int j = 0; j < 4; ++j) {
    tauR[j] = tauB[4 * quad + j];
    izR[j]  = 1.0f / ZB[4 * quad + j];
  }
  sfor<0, CTW>([&](auto ic) {
    constexpr int i = ic.value;
    const int col = wid * 256 + i * 16 + m16;
#pragma unroll
    for (int j = 0; j < 4; ++j) {
      const int row = 4 * quad + j;
      const float tt = fmaxf(acc[i][j] - tauR[j], 0.f);
      if (tt > 0.f) {   // exact: p == 0 otherwise, contributes nothing
        const int pos = atomicAdd(&scnt[row], 1);
        if (pos < 64) { scol[row][pos] = col; sp[row][pos] = tt * tt * izR[j]; }
        else atomicOr(&oflag, 1);
      }
    }
  });
  __syncthreads();

  if ((flagv | oflag) == 0) {
    // ---- phase 4': O[row] = sum_i p_i * V[col_i], fp32, coalesced ----
#pragma unroll
    for (int rr = 0; rr < 2; ++rr) {
      const int row = 2 * wid + rr;
      const int n = min(scnt[row], 64);
      float2 o = {0.f, 0.f};
      for (int i = 0; i < n; ++i) {
        const int   c  = scol[row][i];   // wave-uniform broadcast
        const float pi = sp[row][i];
        const float2 v2 = *(const float2*)&Vb[(size_t)c * DD + lane * 2];
        o.x = fmaf(pi, v2.x, o.x);
        o.y = fmaf(pi, v2.y, o.y);
      }
      *(float2*)&Ob[row * DD + lane * 2] = o;
    }
  } else {
    // ---- dense fallback (unreachable on sane data, correct always) ----
    for (int i = tid; i < ROWS * DD; i += 512) ((float*)obuf)[i] = 0.f;
    __syncthreads();
    sfor<0, CTW>([&](auto ic) {
      constexpr int i = ic.value;
      const int col = wid * 256 + i * 16 + m16;
#pragma unroll
      for (int j = 0; j < 4; ++j) {
        const int row = 4 * quad + j;
        const float tt = fmaxf(acc[i][j] - tauR[j], 0.f);
        const float p = tt * tt * izR[j];
        if (p > 0.f) {
          for (int d = 0; d < DD; ++d)
            atomicAdd(&obuf[row][d], p * Vb[(size_t)col * DD + d]);
        }
      }
    });
    __syncthreads();
    for (int i = tid; i < ROWS * DD; i += 512) {
      const int row = i >> 7, d = i & 127;
      Ob[row * DD + d] = obuf[row][d];
    }
  }
}

extern "C" void kernel_launch(void* const* d_in, const int* in_sizes, int n_in,
                              void* d_out, int out_size, void* d_ws, size_t ws_size,
                              hipStream_t stream) {
  const float* Q = (const float*)d_in[0];
  const float* K = (const float*)d_in[1];
  const float* V = (const float*)d_in[2];
  float* out = (float*)d_out;
  short* Khi = (short*)d_ws;                       // 4 MiB
  short* Klo = Khi + (size_t)BB * SS * DD;         // 4 MiB

  hipLaunchKernelGGL(ksplit, dim3(BB * SS * DD / (256 * 8)), dim3(256), 0, stream,
                     K, Khi, Klo);
  hipLaunchKernelGGL(attn, dim3(BB * (SS / ROWS)), dim3(512), 0, stream,
                     Q, Khi, Klo, V, out);
}

// Round 9
// 155.719 us; speedup vs baseline: 9.8093x; 1.0843x over previous
//
#include <hip/hip_runtime.h>

#define BB 8
#define SS 2048
#define DD 128
#define ROWS 16            // q rows per block
#define NW 8               // waves per block (512 threads)
#define CTW 16             // col-tiles (of 16) per wave -> 256 cols/wave

typedef short bf16x8 __attribute__((ext_vector_type(8)));
typedef float f32x4 __attribute__((ext_vector_type(4)));

template <int I> struct IC { static constexpr int value = I; };
template <int I, int N, typename F>
__device__ __forceinline__ void sfor(F&& f) {
  if constexpr (I < N) { f(IC<I>{}); sfor<I + 1, N>((F&&)f); }
}

__device__ __forceinline__ short f2bf(float x) {
  return __builtin_bit_cast(short, (__bf16)x);
}
__device__ __forceinline__ float bf2f(short u) {
  return __uint_as_float(((unsigned)(unsigned short)u) << 16);
}

// ---- prep: Khi = bf16(K) in MFMA B-fragment order; Klo = residual, ROW-MAJOR bf16 ----
// Frag (b,ct,s,lane): lane(quad,m16) holds K[b][ct*16+m16][s*32+quad*8 .. +8]
__global__ __launch_bounds__(256)
void ksplit(const float* __restrict__ K, short* __restrict__ Khi,
            short* __restrict__ KloRM) {
  const int lin  = blockIdx.x * 256 + threadIdx.x;   // 262144 frags
  const int b    = lin >> 15;
  const int rem  = lin & 32767;
  const int ct   = rem >> 8;
  const int s    = (rem >> 6) & 3;
  const int lane = rem & 63;
  const int quad = lane >> 4, m16 = lane & 15;
  const size_t elem = (size_t)(b * SS + ct * 16 + m16) * DD + s * 32 + quad * 8;
  const float4 v0 = *(const float4*)(K + elem);
  const float4 v1 = *(const float4*)(K + elem + 4);
  const float f[8] = {v0.x, v0.y, v0.z, v0.w, v1.x, v1.y, v1.z, v1.w};
  bf16x8 h, l;
#pragma unroll
  for (int e = 0; e < 8; ++e) {
    h[e] = f2bf(f[e]);
    l[e] = f2bf(f[e] - bf2f(h[e]));
  }
  *(bf16x8*)(Khi + (size_t)lin * 8) = h;      // fragment order
  *(bf16x8*)(KloRM + elem) = l;               // row-major order
}

// ---- fused entmax attention: Khi-only MFMA + exact candidate refinement ----
__global__ __launch_bounds__(512) __attribute__((amdgpu_waves_per_eu(3, 4)))
void attn(const float* __restrict__ Q, const short* __restrict__ Khi,
          const short* __restrict__ KloRM, const float* __restrict__ V,
          float* __restrict__ Out) {
  __shared__ unsigned short Qs[2][ROWS][136];  // split-bf16 Q (0.5 folded)
  __shared__ float rbuf[ROWS][64];             // candidate VALUES (then refined)
  __shared__ int   scol[ROWS][64];             // candidate COLUMNS
  __shared__ float sp[ROWS][64];               // weights (fast path)
  __shared__ float exM[NW][ROWS];
  __shared__ float exZ[NW][ROWS];              // slow bisection only
  __shared__ int   rcnt[ROWS];
  __shared__ float tauB[ROWS], ZB[ROWS];
  __shared__ int   flagv;
  __shared__ float obuf[ROWS][DD];             // dense fallback only

  const int tid  = threadIdx.x;
  const int lane = tid & 63;
  const int wid  = __builtin_amdgcn_readfirstlane(tid >> 6);  // 0..7
  const int quad = lane >> 4, m16 = lane & 15;
  const int b    = blockIdx.x & 7;             // batch -> XCD pinning
  const int qt   = blockIdx.x >> 3;            // 0..127

  const float* Qb = Q + (size_t)(b * SS + qt * ROWS) * DD;
  const float* Vb = V + (size_t)b * SS * DD;
  float*       Ob = Out + (size_t)(b * SS + qt * ROWS) * DD;
  const short* KHb = Khi + (size_t)b * SS * DD;
  const short* KLb = KloRM + (size_t)b * SS * DD;

  if (tid < ROWS) rcnt[tid] = 0;
  if (tid == ROWS) flagv = 0;

  // ---- stage Q once: 0.5*q split hi+lo bf16 (A-operand layout) ----
  {
    const int row = tid >> 5, d = (tid & 31) * 4;
    const float4 v = *(const float4*)&Qb[row * DD + d];
    const float f[4] = {v.x, v.y, v.z, v.w};
    ushort4 h, l;
    unsigned short hh[4], ll[4];
#pragma unroll
    for (int e = 0; e < 4; ++e) {
      const float x = 0.5f * f[e];
      hh[e] = (unsigned short)f2bf(x);
      ll[e] = (unsigned short)f2bf(x - bf2f((short)hh[e]));
    }
    h.x = hh[0]; h.y = hh[1]; h.z = hh[2]; h.w = hh[3];
    l.x = ll[0]; l.y = ll[1]; l.z = ll[2]; l.w = ll[3];
    *(ushort4*)&Qs[0][row][d] = h;
    *(ushort4*)&Qs[1][row][d] = l;
  }
  __syncthreads();

  bf16x8 qh[4], ql[4];
#pragma unroll
  for (int s = 0; s < 4; ++s) {
    qh[s] = *(const bf16x8*)&Qs[0][m16][s * 32 + quad * 8];
    ql[s] = *(const bf16x8*)&Qs[1][m16][s * 32 + quad * 8];
  }

  // ---- phase 1: z_a = (0.5Q)Khi^T, 2-term split-bf16, B-frags from global ----
  f32x4 acc[CTW];
  sfor<0, CTW>([&](auto ic) {
    constexpr int i = ic.value;
    const int ct = wid * CTW + i;
    const short* bh0 = KHb + ((size_t)ct << 11) + lane * 8;
    f32x4 c = {0.f, 0.f, 0.f, 0.f};
    sfor<0, 4>([&](auto sc) {
      constexpr int s = sc.value;
      const bf16x8 bh = *(const bf16x8*)(bh0 + (s << 9));
      c = __builtin_amdgcn_mfma_f32_16x16x32_bf16(qh[s], bh, c, 0, 0, 0);
      c = __builtin_amdgcn_mfma_f32_16x16x32_bf16(ql[s], bh, c, 0, 0, 0);
    });
    acc[i] = c;
  });
  // lane holds z_a[row=4*quad+j][col = wid*256 + i*16 + m16]; |z_a - z| std ~0.0064

  // ---- row max of z_a ----
  float mx[4] = {-1e38f, -1e38f, -1e38f, -1e38f};
  sfor<0, CTW>([&](auto ic) {
#pragma unroll
    for (int j = 0; j < 4; ++j) mx[j] = fmaxf(mx[j], acc[ic.value][j]);
  });
#pragma unroll
  for (int j = 0; j < 4; ++j)
#pragma unroll
    for (int s = 1; s <= 8; s <<= 1) mx[j] = fmaxf(mx[j], __shfl_xor(mx[j], s));
  if (m16 == 0) {
#pragma unroll
    for (int j = 0; j < 4; ++j) exM[wid][4 * quad + j] = mx[j];
  }
  __syncthreads();
  float M4[4];
#pragma unroll
  for (int j = 0; j < 4; ++j) {
    float m = -1e38f;
#pragma unroll
    for (int w = 0; w < NW; ++w) m = fmaxf(m, exM[w][4 * quad + j]);
    M4[j] = m;
  }

  // ---- compact candidates: z_a > M_a - 1.1 (margin = 1 + 2*5sigma of z_a err) ----
  sfor<0, CTW>([&](auto ic) {
    constexpr int i = ic.value;
    const int col = wid * 256 + i * 16 + m16;
#pragma unroll
    for (int j = 0; j < 4; ++j) {
      const int row = 4 * quad + j;
      if (acc[i][j] > M4[j] - 1.1f) {
        const int pos = atomicAdd(&rcnt[row], 1);
        if (pos < 64) { scol[row][pos] = col; rbuf[row][pos] = acc[i][j]; }
        else atomicOr(&flagv, 1);
      }
    }
  });
  __syncthreads();

  // ---- refine candidates to fp32 accuracy: z = z_a + 0.5*dot(Q, Klo[c]) ----
  if (flagv == 0) {
#pragma unroll
    for (int rr = 0; rr < 2; ++rr) {
      const int row = 2 * wid + rr;
      const int n = rcnt[row];
      const float2 q2 = *(const float2*)&Qb[row * DD + lane * 2];
      for (int i = 0; i < n; ++i) {
        const int c = scol[row][i];
        const unsigned u = *(const unsigned*)(KLb + (size_t)c * DD + lane * 2);
        const float klx = __uint_as_float((u & 0xffffu) << 16);
        const float kly = __uint_as_float(u & 0xffff0000u);
        float t = q2.x * klx + q2.y * kly;
#pragma unroll
        for (int s = 1; s <= 32; s <<= 1) t += __shfl_xor(t, s);
        if (lane == 0) rbuf[row][i] += 0.5f * t;
      }
    }
  }
  __syncthreads();

  // ---- bisection ----
  float tau4[4], Z4[4];   // slow path state
  if (flagv == 0) {
    // fast: all waves redundantly bisect all 16 rows on refined candidate lists
    const int row = lane >> 2;
    const int n = rcnt[row];
    float Mr = -1e38f;
    for (int i = (lane & 3); i < n; i += 4) Mr = fmaxf(Mr, rbuf[row][i]);
    Mr = fmaxf(Mr, __shfl_xor(Mr, 1));
    Mr = fmaxf(Mr, __shfl_xor(Mr, 2));
    float tmn = Mr - 1.0f, tmx = Mr - 0.022097086912079608f;  // S^(1-alpha)
    float tau = 0.5f * (tmn + tmx), Zr = 0.f;
    for (int it = 0; it < 100; ++it) {
      tau = 0.5f * (tmn + tmx);
      float zp = 0.f;
      for (int i = (lane & 3); i < n; i += 4) {
        float tt = fmaxf(rbuf[row][i] - tau, 0.f);
        zp = fmaf(tt, tt, zp);
      }
      zp += __shfl_xor(zp, 1);
      zp += __shfl_xor(zp, 2);
      Zr = zp;
      float nmn = (zp >= 1.f) ? tau : tmn;
      float nmx = (zp >= 1.f) ? tmx : tau;
      bool ch = (nmn != tmn) || (nmx != tmx);
      tmn = nmn; tmx = nmx;
      if (!__any(ch)) break;   // fixed point: faithful to 100 iters
    }
    if (wid == 0 && (lane & 3) == 0) { tauB[row] = tau; ZB[row] = Zr; }
  } else {
    // slow: dense bisection on z_a (unreachable on sane data)
    float tmn4[4], tmx4[4];
#pragma unroll
    for (int j = 0; j < 4; ++j) {
      tmn4[j] = M4[j] - 1.0f; tmx4[j] = M4[j] - 0.022097086912079608f;
      tau4[j] = 0.5f * (tmn4[j] + tmx4[j]); Z4[j] = 0.f;
    }
    for (int it = 0; it < 100; ++it) {
      float zp[4] = {0.f, 0.f, 0.f, 0.f};
#pragma unroll
      for (int j = 0; j < 4; ++j) tau4[j] = 0.5f * (tmn4[j] + tmx4[j]);
      sfor<0, CTW>([&](auto ic) {
#pragma unroll
        for (int j = 0; j < 4; ++j) {
          const float tt = fmaxf(acc[ic.value][j] - tau4[j], 0.f);
          zp[j] = fmaf(tt, tt, zp[j]);
        }
      });
#pragma unroll
      for (int j = 0; j < 4; ++j)
#pragma unroll
        for (int s = 1; s <= 8; s <<= 1) zp[j] += __shfl_xor(zp[j], s);
      if (m16 == 0) {
#pragma unroll
        for (int j = 0; j < 4; ++j) exZ[wid][4 * quad + j] = zp[j];
      }
      __syncthreads();
      bool ch = false;
#pragma unroll
      for (int j = 0; j < 4; ++j) {
        float Zf = 0.f;
#pragma unroll
        for (int w = 0; w < NW; ++w) Zf += exZ[w][4 * quad + j];
        Z4[j] = Zf;
        const float nmn = (Zf >= 1.f) ? tau4[j] : tmn4[j];
        const float nmx = (Zf >= 1.f) ? tmx4[j] : tau4[j];
        ch = ch || (nmn != tmn4[j]) || (nmx != tmx4[j]);
        tmn4[j] = nmn; tmx4[j] = nmx;
      }
      __syncthreads();
      if (!ch) break;          // Zf block-uniform -> barrier-safe
    }
  }
  __syncthreads();

  if (flagv == 0) {
    // ---- weights then O = sum p_i * V[col_i], fp32, coalesced ----
#pragma unroll
    for (int rr = 0; rr < 2; ++rr) {
      const int row = 2 * wid + rr;
      const int n = rcnt[row];
      const float tau = tauB[row];
      const float iz  = 1.0f / ZB[row];
      for (int i = lane; i < n; i += 64) {
        const float tt = fmaxf(rbuf[row][i] - tau, 0.f);
        sp[row][i] = tt * tt * iz;
      }
      // sp written and read by this same wave only -> no barrier needed
      float2 o = {0.f, 0.f};
      for (int i = 0; i < n; ++i) {
        const float pi = sp[row][i];
        const int   c  = scol[row][i];
        const float2 v2 = *(const float2*)&Vb[(size_t)c * DD + lane * 2];
        o.x = fmaf(pi, v2.x, o.x);
        o.y = fmaf(pi, v2.y, o.y);
      }
      *(float2*)&Ob[row * DD + lane * 2] = o;
    }
  } else {
    // ---- dense fallback output from z_a ----
    for (int i = tid; i < ROWS * DD; i += 512) ((float*)obuf)[i] = 0.f;
    __syncthreads();
    sfor<0, CTW>([&](auto ic) {
      constexpr int i = ic.value;
      const int col = wid * 256 + i * 16 + m16;
#pragma unroll
      for (int j = 0; j < 4; ++j) {
        const int row = 4 * quad + j;
        const float tt = fmaxf(acc[i][j] - tau4[j], 0.f);
        const float p = tt * tt / Z4[j];
        if (p > 0.f) {
          for (int d = 0; d < DD; ++d)
            atomicAdd(&obuf[row][d], p * Vb[(size_t)col * DD + d]);
        }
      }
    });
    __syncthreads();
    for (int i = tid; i < ROWS * DD; i += 512) {
      const int row = i >> 7, d = i & 127;
      Ob[row * DD + d] = obuf[row][d];
    }
  }
}

extern "C" void kernel_launch(void* const* d_in, const int* in_sizes, int n_in,
                              void* d_out, int out_size, void* d_ws, size_t ws_size,
                              hipStream_t stream) {
  const float* Q = (const float*)d_in[0];
  const float* K = (const float*)d_in[1];
  const float* V = (const float*)d_in[2];
  float* out = (float*)d_out;
  short* Khi   = (short*)d_ws;                     // 4 MiB, fragment order
  short* KloRM = Khi + (size_t)BB * SS * DD;       // 4 MiB, row-major

  hipLaunchKernelGGL(ksplit, dim3(BB * SS * DD / (256 * 8)), dim3(256), 0, stream,
                     K, Khi, KloRM);
  hipLaunchKernelGGL(attn, dim3(BB * (SS / ROWS)), dim3(512), 0, stream,
                     Q, Khi, KloRM, V, out);
}